// Round 8
// baseline (483.663 us; speedup 1.0000x reference)
//
#include <hip/hip_runtime.h>
#include <hip/hip_bf16.h>

typedef __bf16 bf16;
typedef __bf16 bf16x4 __attribute__((ext_vector_type(4)));
typedef __bf16 bf16x8 __attribute__((ext_vector_type(8)));
typedef float f32x4 __attribute__((ext_vector_type(4)));

constexpr int N_NODES  = 100000;
constexpr int N_EDGES  = 800000;
constexpr int N_GRAPHS = 512;
constexpr int D_IN  = 300;
constexpr int D_HID = 300;
constexpr int D_OUT = 128;
constexpr int KP    = 320;   // padded feature stride
constexpr int MT    = 128;   // GEMM M-tile rows
constexpr int NTILE = (N_NODES + MT - 1) / MT;   // 782
constexpr int NPAD  = NTILE * MT;                // 100096

#define AS1(p) ((const __attribute__((address_space(1))) void*)(p))
#define AS3(p) ((__attribute__((address_space(3))) void*)(p))

// ---------------- setup kernels ----------------

__global__ __launch_bounds__(256) void k_init(int* deg, float* gsum, int* cnt) {
  int i = blockIdx.x * 256 + threadIdx.x;
  if (i < N_NODES) deg[i] = 0;
  if (i < N_GRAPHS) { gsum[i] = 0.f; cnt[i] = 0; }
}

__global__ __launch_bounds__(256) void k_deg(const int* __restrict__ ei, int* __restrict__ deg) {
  int e = blockIdx.x * 256 + threadIdx.x;
  if (e < N_EDGES) atomicAdd(&deg[ei[N_EDGES + e]], 1);
}

__global__ __launch_bounds__(256) void k_dinv(const int* __restrict__ deg, float* __restrict__ dinv) {
  int v = blockIdx.x * 256 + threadIdx.x;
  if (v < N_NODES) dinv[v] = rsqrtf((float)(deg[v] + 1));  // +1 self loop
}

__global__ __launch_bounds__(256) void k_scan1(const int* __restrict__ deg, int* __restrict__ rp,
                                               int* __restrict__ part) {
  __shared__ int sm[256];
  int tid = threadIdx.x;
  int i = blockIdx.x * 256 + tid;
  int v = (i < N_NODES) ? deg[i] : 0;
  sm[tid] = v;
  __syncthreads();
  for (int off = 1; off < 256; off <<= 1) {
    int t = (tid >= off) ? sm[tid - off] : 0;
    __syncthreads();
    sm[tid] += t;
    __syncthreads();
  }
  if (i < N_NODES) rp[i] = sm[tid] - v;
  if (tid == 255) part[blockIdx.x] = sm[255];
}

__global__ __launch_bounds__(512) void k_scan2(int* part, int nb) {
  __shared__ int sm[512];
  int tid = threadIdx.x;
  int v = (tid < nb) ? part[tid] : 0;
  sm[tid] = v;
  __syncthreads();
  for (int off = 1; off < 512; off <<= 1) {
    int t = (tid >= off) ? sm[tid - off] : 0;
    __syncthreads();
    sm[tid] += t;
    __syncthreads();
  }
  if (tid < nb) part[tid] = sm[tid] - v;
}

__global__ __launch_bounds__(256) void k_scan3(int* __restrict__ rp, const int* __restrict__ part,
                                               int* __restrict__ cur) {
  int i = blockIdx.x * 256 + threadIdx.x;
  if (i < N_NODES) {
    int r = rp[i] + part[blockIdx.x];
    rp[i] = r;
    cur[i] = r;
  }
  if (i == 0) rp[N_NODES] = N_EDGES;
}

__global__ __launch_bounds__(256) void k_fill(const int* __restrict__ ei, int* __restrict__ cur,
                                              int* __restrict__ col) {
  int e = blockIdx.x * 256 + threadIdx.x;
  if (e < N_EDGES) {
    int s = ei[e];
    int d = ei[N_EDGES + e];
    int p = atomicAdd(&cur[d], 1);
    col[p] = s;
  }
}

// ---------------- conversions ----------------

// Xs[v][k] = dinv[v] * x[v][k] as bf16, zero-padded to KP
__global__ __launch_bounds__(256) void k_conv_x(const float* __restrict__ x, const float* __restrict__ dinv,
                                                bf16* __restrict__ Xs) {
  int i = blockIdx.x * 256 + threadIdx.x;       // over N_NODES*80
  if (i >= N_NODES * (KP / 4)) return;
  int j = i % (KP / 4);
  int v = i / (KP / 4);
  float4 f = make_float4(0.f, 0.f, 0.f, 0.f);
  if (j < D_IN / 4) f = ((const float4*)(x + (size_t)v * D_IN))[j];
  float dv = dinv[v];
  bf16x4 o;
  o[0] = (bf16)(f.x * dv); o[1] = (bf16)(f.y * dv); o[2] = (bf16)(f.z * dv); o[3] = (bf16)(f.w * dv);
  *(bf16x4*)(Xs + (size_t)v * KP + j * 4) = o;
}

// Wt[n][k] = W[k][n], zero-padded to [KP][KP]
__global__ __launch_bounds__(256) void k_conv_w(const float* __restrict__ W, bf16* __restrict__ Wt,
                                                int Kin, int Nin) {
  int i = blockIdx.x * 256 + threadIdx.x;
  if (i >= KP * KP) return;
  int k = i % KP;
  int n = i / KP;
  float f = (k < Kin && n < Nin) ? W[k * Nin + n] : 0.f;
  Wt[i] = (bf16)f;
}

// ---------------- aggregation (pre-GEMM, bf16): out[v] = dinv[v]*(sum_nbr in[u] + in[v]) ----------------
// R4 form (VGPR 32, occ ~73%): lanes 0..39 own 8 cols; x4 unroll, 2 acc sets.

__global__ __launch_bounds__(256) void k_aggb(const bf16* __restrict__ in, const int* __restrict__ rp,
                                              const int* __restrict__ col, const float* __restrict__ dinv,
                                              bf16* __restrict__ out) {
  int w = threadIdx.x >> 6, l = threadIdx.x & 63;
  int v = blockIdx.x * 4 + w;
  if (v >= N_NODES) return;
  if (l >= 40) return;                         // 40 lanes x 8 cols = 320
  const size_t co = (size_t)8 * l;

  float A0[8], A1[8];
  {                                            // init with self row
    bf16x8 p = *(const bf16x8*)(in + (size_t)v * KP + co);
#pragma unroll
    for (int j = 0; j < 8; ++j) { A0[j] = (float)p[j]; A1[j] = 0.f; }
  }
  int s = rp[v], e = rp[v + 1];
  int i = s;
  for (; i + 4 <= e; i += 4) {
    int u0 = col[i], u1 = col[i + 1], u2 = col[i + 2], u3 = col[i + 3];
    bf16x8 p0 = *(const bf16x8*)(in + (size_t)u0 * KP + co);
    bf16x8 p1 = *(const bf16x8*)(in + (size_t)u1 * KP + co);
    bf16x8 p2 = *(const bf16x8*)(in + (size_t)u2 * KP + co);
    bf16x8 p3 = *(const bf16x8*)(in + (size_t)u3 * KP + co);
#pragma unroll
    for (int j = 0; j < 8; ++j) {
      A0[j] += (float)p0[j] + (float)p2[j];
      A1[j] += (float)p1[j] + (float)p3[j];
    }
  }
  for (; i + 2 <= e; i += 2) {
    int u0 = col[i], u1 = col[i + 1];
    bf16x8 p0 = *(const bf16x8*)(in + (size_t)u0 * KP + co);
    bf16x8 p1 = *(const bf16x8*)(in + (size_t)u1 * KP + co);
#pragma unroll
    for (int j = 0; j < 8; ++j) { A0[j] += (float)p0[j]; A1[j] += (float)p1[j]; }
  }
  if (i < e) {
    int u0 = col[i];
    bf16x8 p0 = *(const bf16x8*)(in + (size_t)u0 * KP + co);
#pragma unroll
    for (int j = 0; j < 8; ++j) A0[j] += (float)p0[j];
  }
  float dv = dinv[v];
  bf16x8 o;
#pragma unroll
  for (int j = 0; j < 8; ++j) o[j] = (bf16)((A0[j] + A1[j]) * dv);
  *(bf16x8*)(out + (size_t)v * KP + co) = o;
}

// ---------------- layer-3 post-GEMM aggregation ----------------
// T3: [NPAD][128] bf16. T3[u] = (H·W3)[u] = dinv[u]*(h2·W3)[u] — already gather-prescaled.
// sArr[v] = sum_d relu(dinv[v]*(sum_nbr T3[u] + T3[v])[d] + b3[d]) * Wm[d]

__global__ __launch_bounds__(256) void k_agg3(const bf16* __restrict__ T3, const int* __restrict__ rp,
                                              const int* __restrict__ col, const float* __restrict__ dinv,
                                              const float* __restrict__ bias, const float* __restrict__ Wm,
                                              float* __restrict__ sArr) {
  const int tid = threadIdx.x;
  const int c = tid & 15;                      // 16B chunk within row
  const int v = blockIdx.x * 16 + (tid >> 4);  // grid is exactly N_NODES/16
  const size_t co = (size_t)8 * c;

  float A0[8], A1[8];
  {                                            // self row
    bf16x8 p = *(const bf16x8*)(T3 + (size_t)v * 128 + co);
#pragma unroll
    for (int j = 0; j < 8; ++j) { A0[j] = (float)p[j]; A1[j] = 0.f; }
  }
  int s = rp[v], e = rp[v + 1];
  int i = s;
  for (; i + 4 <= e; i += 4) {
    int u0 = col[i], u1 = col[i + 1], u2 = col[i + 2], u3 = col[i + 3];
    bf16x8 p0 = *(const bf16x8*)(T3 + (size_t)u0 * 128 + co);
    bf16x8 p1 = *(const bf16x8*)(T3 + (size_t)u1 * 128 + co);
    bf16x8 p2 = *(const bf16x8*)(T3 + (size_t)u2 * 128 + co);
    bf16x8 p3 = *(const bf16x8*)(T3 + (size_t)u3 * 128 + co);
#pragma unroll
    for (int j = 0; j < 8; ++j) {
      A0[j] += (float)p0[j] + (float)p2[j];
      A1[j] += (float)p1[j] + (float)p3[j];
    }
  }
  for (; i + 2 <= e; i += 2) {
    int u0 = col[i], u1 = col[i + 1];
    bf16x8 p0 = *(const bf16x8*)(T3 + (size_t)u0 * 128 + co);
    bf16x8 p1 = *(const bf16x8*)(T3 + (size_t)u1 * 128 + co);
#pragma unroll
    for (int j = 0; j < 8; ++j) { A0[j] += (float)p0[j]; A1[j] += (float)p1[j]; }
  }
  if (i < e) {
    bf16x8 p0 = *(const bf16x8*)(T3 + (size_t)col[i] * 128 + co);
#pragma unroll
    for (int j = 0; j < 8; ++j) A0[j] += (float)p0[j];
  }

  float dv = dinv[v];
  float sv = 0.f;
#pragma unroll
  for (int j = 0; j < 8; ++j) {
    int d = (int)co + j;
    float val = fmaxf((A0[j] + A1[j]) * dv + bias[d], 0.f);
    sv += val * Wm[d];
  }
#pragma unroll
  for (int m = 1; m < 16; m <<= 1) sv += __shfl_xor(sv, m);  // reduce within 16-lane group
  if (c == 0) sArr[v] = sv;
}

// ---------------- GEMM: 2-phase pipelined, M-tile 128 x NP, BK=32, double-buffered LDS ----------------
// A: [NPAD][KP] bf16 k-contig. Bt: [KP][KP] bf16 n-major k-contig.
// LDS rows are 64B (BK=32); 16B slot s holds global slot s^(row&3) (pre-swizzled source,
// linear gload_lds dest); ds_read applies the same XOR -> every 16B-quad gets exactly 8/64 lanes.
// Pipeline: STAGE(kh+1 -> buf^1) issued BEFORE compute(buf); ONE barrier per K-chunk.
// EPI 0: H[row][c] = dinv[row]*relu(acc + bias[c])   (bf16, stride KP)
// EPI 1: T3[row][c] = acc                            (bf16, stride NP; input rows carry dinv)

template <int NP, int WM, int WN, int EPI>
__global__ __launch_bounds__(512, 4) void k_gemm(const bf16* __restrict__ A, const bf16* __restrict__ Bt,
                                                 const float* __restrict__ dinv, const float* __restrict__ bias,
                                                 bf16* __restrict__ H) {
  constexpr int WROWS = MT / WM;
  constexpr int MI    = WROWS / 16;
  constexpr int WCOLS = NP / WN;
  constexpr int NC    = WCOLS / 16;
  constexpr int BCH   = NP * 4;          // 16B chunks per B buffer
  constexpr int SB    = NP * 64;         // B buffer bytes
  constexpr int NK    = KP / 32;         // 10 K-chunks
  __shared__ __attribute__((aligned(16))) char sA[2 * MT * 64];   // 16 KB
  __shared__ __attribute__((aligned(16))) char sB[2 * SB];        // 40/16 KB

  const int tid = threadIdx.x;
  const int w = tid >> 6, l = tid & 63;
  const int wm = w / WN, wn = w % WN;
  const int m0 = blockIdx.x * MT;
  const int la = l & 15, q = l >> 4;

  const char* Ab = (const char*)A;
  const char* Bb = (const char*)Bt;
  // A staging: 512 chunks, 1/thread; chunk tid -> row tid>>2, slot tid&3 (source pre-swizzled)
  const int ar_ = tid >> 2, as_ = tid & 3;
  const size_t a_src = (size_t)(m0 + ar_) * 640 + (size_t)((as_ ^ (ar_ & 3)) << 4);

  f32x4 acc[MI][NC] = {};

  auto STAGE = [&](int kh, int buf) {
    __builtin_amdgcn_global_load_lds(AS1(Ab + a_src + kh * 64),
                                     AS3(sA + buf * (MT * 64) + (w * 64) * 16), 16, 0, 0);
#pragma unroll
    for (int j = 0; j < (BCH + 511) / 512; ++j) {
      int cbase = j * 512 + w * 64;              // wave-uniform
      if (cbase < BCH) {
        int c = cbase + l;
        int r = c >> 2, s = c & 3;
        const char* src = Bb + (size_t)r * 640 + kh * 64 + ((s ^ (r & 3)) << 4);
        __builtin_amdgcn_global_load_lds(AS1(src), AS3(sB + buf * SB + cbase * 16), 16, 0, 0);
      }
    }
  };

  STAGE(0, 0);
  __syncthreads();

  for (int kh = 0; kh < NK; ++kh) {
    const int buf = kh & 1;
    if (kh + 1 < NK) STAGE(kh + 1, buf ^ 1);     // issue next-chunk loads (into other buffer)

    const char* aB = sA + buf * (MT * 64);
    const char* bB = sB + buf * SB;
    bf16x8 af[MI];
#pragma unroll
    for (int mi = 0; mi < MI; ++mi) {
      int ar = wm * WROWS + mi * 16 + la;
      af[mi] = *(const bf16x8*)(aB + ar * 64 + ((q ^ (ar & 3)) << 4));
    }
#pragma unroll
    for (int nc = 0; nc < NC; ++nc) {
      int rb = wn * WCOLS + nc * 16 + la;
      bf16x8 bfr = *(const bf16x8*)(bB + rb * 64 + ((q ^ (rb & 3)) << 4));
#pragma unroll
      for (int mi = 0; mi < MI; ++mi)
        acc[mi][nc] = __builtin_amdgcn_mfma_f32_16x16x32_bf16(af[mi], bfr, acc[mi][nc], 0, 0, 0);
    }
    __syncthreads();                             // drains stage vmcnt; readers done before overwrite
  }

  // C/D layout: col = lane&15, row = (lane>>4)*4 + reg
  const int rbase = m0 + wm * WROWS + q * 4;
  if (EPI == 0) {
    float bc[NC];
#pragma unroll
    for (int nc = 0; nc < NC; ++nc) {
      int c = wn * WCOLS + nc * 16 + la;
      bc[nc] = (c < D_HID) ? bias[c] : 0.f;      // pad cols: acc=0, bias=0 -> stores 0
    }
#pragma unroll
    for (int mi = 0; mi < MI; ++mi) {
#pragma unroll
      for (int r = 0; r < 4; ++r) {
        int row = rbase + mi * 16 + r;
        if (row < N_NODES) {
          float dv = dinv[row];
#pragma unroll
          for (int nc = 0; nc < NC; ++nc) {
            int c = wn * WCOLS + nc * 16 + la;
            H[(size_t)row * KP + c] = (bf16)(fmaxf(acc[mi][nc][r] + bc[nc], 0.f) * dv);
          }
        }
      }
    }
  } else {
#pragma unroll
    for (int mi = 0; mi < MI; ++mi) {
#pragma unroll
      for (int r = 0; r < 4; ++r) {
        int row = rbase + mi * 16 + r;
        if (row < N_NODES) {
#pragma unroll
          for (int nc = 0; nc < NC; ++nc) {
            int c = wn * WCOLS + nc * 16 + la;
            H[(size_t)row * NP + c] = (bf16)acc[mi][nc][r];   // NO dinv: input rows already scaled
          }
        }
      }
    }
  }
}

// ---------------- pooled reduction ----------------

__global__ __launch_bounds__(256) void k_gsum(const float* __restrict__ sArr, const int* __restrict__ batch,
                                              float* __restrict__ gsum, int* __restrict__ cnt) {
  __shared__ float lsum[N_GRAPHS];
  __shared__ int   lcnt[N_GRAPHS];
  int tid = threadIdx.x;
  lsum[tid] = 0.f; lsum[tid + 256] = 0.f;
  lcnt[tid] = 0;   lcnt[tid + 256] = 0;
  __syncthreads();
  int v = blockIdx.x * 256 + tid;
  if (v < N_NODES) {
    int b = batch[v];
    atomicAdd(&lsum[b], sArr[v]);
    atomicAdd(&lcnt[b], 1);
  }
  __syncthreads();
  for (int g = tid; g < N_GRAPHS; g += 256) {
    int c = lcnt[g];
    if (c) { atomicAdd(&gsum[g], lsum[g]); atomicAdd(&cnt[g], c); }
  }
}

__global__ __launch_bounds__(512) void k_final(const float* __restrict__ gsum, const int* __restrict__ cnt,
                                               const float* __restrict__ bm, float* __restrict__ out) {
  int g = blockIdx.x * 512 + threadIdx.x;
  if (g < N_GRAPHS) out[g] = gsum[g] / fmaxf((float)cnt[g], 1.f) + bm[0];
}

// ---------------- launch ----------------

extern "C" void kernel_launch(void* const* d_in, const int* in_sizes, int n_in,
                              void* d_out, int out_size, void* d_ws, size_t ws_size,
                              hipStream_t stream) {
  const float* x    = (const float*)d_in[0];
  const int*   ei   = (const int*)d_in[1];
  const int*   batch= (const int*)d_in[2];
  const float* W1   = (const float*)d_in[3];
  const float* b1   = (const float*)d_in[4];
  const float* W2   = (const float*)d_in[5];
  const float* b2   = (const float*)d_in[6];
  const float* W3   = (const float*)d_in[7];
  const float* b3   = (const float*)d_in[8];
  const float* Wm   = (const float*)d_in[9];
  const float* bm   = (const float*)d_in[10];
  float* out = (float*)d_out;

  char* ws = (char*)d_ws;
  size_t off = 0;
  auto alloc = [&](size_t bytes) {
    void* p = ws + off;
    off = (off + bytes + 255) & ~(size_t)255;
    return p;
  };
  bf16*  Xs   = (bf16*)alloc((size_t)NPAD * KP * sizeof(bf16));    // 64 MB; reused as H
  bf16*  Ab   = (bf16*)alloc((size_t)NPAD * KP * sizeof(bf16));    // 64 MB
  bf16*  T3   = (bf16*)alloc((size_t)NPAD * 128 * sizeof(bf16));   // 25.6 MB
  bf16*  Wt   = (bf16*)alloc((size_t)KP * KP * sizeof(bf16));
  int*   deg  = (int*)alloc((size_t)N_NODES * 4);
  float* dinv = (float*)alloc((size_t)N_NODES * 4);
  int*   rp   = (int*)alloc((size_t)(N_NODES + 1) * 4);
  int*   cur  = (int*)alloc((size_t)N_NODES * 4);
  int*   col  = (int*)alloc((size_t)N_EDGES * 4);
  int*   part = (int*)alloc(1024 * 4);
  float* sArr = (float*)alloc((size_t)N_NODES * 4);
  float* gsum = (float*)alloc((size_t)N_GRAPHS * 4);
  int*   cnt  = (int*)alloc((size_t)N_GRAPHS * 4);
  bf16*  H    = Xs;   // Xs dead after layer-1 agg

  int nbN = (N_NODES + 255) / 256;   // 391
  int nbE = (N_EDGES + 255) / 256;   // 3125
  int nbA = (N_NODES + 3) / 4;       // 25000
  int nbW = (KP * KP + 255) / 256;

  k_init<<<nbN, 256, 0, stream>>>(deg, gsum, cnt);
  k_deg<<<nbE, 256, 0, stream>>>(ei, deg);
  k_dinv<<<nbN, 256, 0, stream>>>(deg, dinv);
  k_scan1<<<nbN, 256, 0, stream>>>(deg, rp, part);
  k_scan2<<<1, 512, 0, stream>>>(part, nbN);
  k_scan3<<<nbN, 256, 0, stream>>>(rp, part, cur);
  k_fill<<<nbE, 256, 0, stream>>>(ei, cur, col);
  k_conv_x<<<(N_NODES * (KP / 4) + 255) / 256, 256, 0, stream>>>(x, dinv, Xs);

  // layer 1: aggregate (bf16) -> GEMM (bias+relu+dinv)
  k_conv_w<<<nbW, 256, 0, stream>>>(W1, Wt, 300, 300);
  k_aggb<<<nbA, 256, 0, stream>>>(Xs, rp, col, dinv, Ab);
  k_gemm<KP, 2, 4, 0><<<NTILE, 512, 0, stream>>>(Ab, Wt, dinv, b1, H);
  // layer 2
  k_conv_w<<<nbW, 256, 0, stream>>>(W2, Wt, 300, 300);
  k_aggb<<<nbA, 256, 0, stream>>>(H, rp, col, dinv, Ab);
  k_gemm<KP, 2, 4, 0><<<NTILE, 512, 0, stream>>>(Ab, Wt, dinv, b2, H);
  // layer 3: GEMM first (128-wide; H rows already dinv-scaled), then aggregate + bias + relu + Wm-dot
  k_conv_w<<<nbW, 256, 0, stream>>>(W3, Wt, 300, 128);
  k_gemm<128, 8, 1, 1><<<NTILE, 512, 0, stream>>>(H, Wt, dinv, nullptr, T3);
  k_agg3<<<N_NODES / 16, 256, 0, stream>>>(T3, rp, col, dinv, b3, Wm, sArr);

  k_gsum<<<nbN, 256, 0, stream>>>(sArr, batch, gsum, cnt);
  k_final<<<1, 512, 0, stream>>>(gsum, cnt, bm, out);
}

// Round 9
// 444.865 us; speedup vs baseline: 1.0872x; 1.0872x over previous
//
#include <hip/hip_runtime.h>
#include <hip/hip_bf16.h>

typedef __bf16 bf16;
typedef __bf16 bf16x4 __attribute__((ext_vector_type(4)));
typedef __bf16 bf16x8 __attribute__((ext_vector_type(8)));
typedef float f32x4 __attribute__((ext_vector_type(4)));

constexpr int N_NODES  = 100000;
constexpr int N_EDGES  = 800000;
constexpr int N_GRAPHS = 512;
constexpr int D_IN  = 300;
constexpr int D_HID = 300;
constexpr int D_OUT = 128;
constexpr int KP    = 320;   // padded feature stride
constexpr int MT    = 128;   // GEMM M-tile rows
constexpr int NTILE = (N_NODES + MT - 1) / MT;   // 782
constexpr int NPAD  = NTILE * MT;                // 100096

#define AS1(p) ((const __attribute__((address_space(1))) void*)(p))
#define AS3(p) ((__attribute__((address_space(3))) void*)(p))

// ---------------- setup kernels ----------------

__global__ __launch_bounds__(256) void k_init(int* deg, float* gsum, int* cnt) {
  int i = blockIdx.x * 256 + threadIdx.x;
  if (i < N_NODES) deg[i] = 0;
  if (i < N_GRAPHS) { gsum[i] = 0.f; cnt[i] = 0; }
}

// 4 edges per thread, int4 loads
__global__ __launch_bounds__(256) void k_deg(const int* __restrict__ ei, int* __restrict__ deg) {
  int e4 = blockIdx.x * 256 + threadIdx.x;
  if (e4 < N_EDGES / 4) {
    int4 d4 = ((const int4*)(ei + N_EDGES))[e4];
    atomicAdd(&deg[d4.x], 1);
    atomicAdd(&deg[d4.y], 1);
    atomicAdd(&deg[d4.z], 1);
    atomicAdd(&deg[d4.w], 1);
  }
}

__global__ __launch_bounds__(256) void k_scan1(const int* __restrict__ deg, int* __restrict__ rp,
                                               int* __restrict__ part) {
  __shared__ int sm[256];
  int tid = threadIdx.x;
  int i = blockIdx.x * 256 + tid;
  int v = (i < N_NODES) ? deg[i] : 0;
  sm[tid] = v;
  __syncthreads();
  for (int off = 1; off < 256; off <<= 1) {
    int t = (tid >= off) ? sm[tid - off] : 0;
    __syncthreads();
    sm[tid] += t;
    __syncthreads();
  }
  if (i < N_NODES) rp[i] = sm[tid] - v;
  if (tid == 255) part[blockIdx.x] = sm[255];
}

__global__ __launch_bounds__(512) void k_scan2(int* part, int nb) {
  __shared__ int sm[512];
  int tid = threadIdx.x;
  int v = (tid < nb) ? part[tid] : 0;
  sm[tid] = v;
  __syncthreads();
  for (int off = 1; off < 512; off <<= 1) {
    int t = (tid >= off) ? sm[tid - off] : 0;
    __syncthreads();
    sm[tid] += t;
    __syncthreads();
  }
  if (tid < nb) part[tid] = sm[tid] - v;
}

// scan finalize + dinv fused (one fewer dispatch)
__global__ __launch_bounds__(256) void k_scan3(int* __restrict__ rp, const int* __restrict__ part,
                                               int* __restrict__ cur, const int* __restrict__ deg,
                                               float* __restrict__ dinv) {
  int i = blockIdx.x * 256 + threadIdx.x;
  if (i < N_NODES) {
    int r = rp[i] + part[blockIdx.x];
    rp[i] = r;
    cur[i] = r;
    dinv[i] = rsqrtf((float)(deg[i] + 1));   // +1 self loop
  }
  if (i == 0) rp[N_NODES] = N_EDGES;
}

// 4 edges per thread, int4 loads
__global__ __launch_bounds__(256) void k_fill(const int* __restrict__ ei, int* __restrict__ cur,
                                              int* __restrict__ col) {
  int e4 = blockIdx.x * 256 + threadIdx.x;
  if (e4 < N_EDGES / 4) {
    int4 s4 = ((const int4*)ei)[e4];
    int4 d4 = ((const int4*)(ei + N_EDGES))[e4];
    col[atomicAdd(&cur[d4.x], 1)] = s4.x;
    col[atomicAdd(&cur[d4.y], 1)] = s4.y;
    col[atomicAdd(&cur[d4.z], 1)] = s4.z;
    col[atomicAdd(&cur[d4.w], 1)] = s4.w;
  }
}

// ---------------- conversions ----------------

// Xs[v][k] = dinv[v] * x[v][k] as bf16, zero-padded to KP
__global__ __launch_bounds__(256) void k_conv_x(const float* __restrict__ x, const float* __restrict__ dinv,
                                                bf16* __restrict__ Xs) {
  int i = blockIdx.x * 256 + threadIdx.x;       // over N_NODES*80
  if (i >= N_NODES * (KP / 4)) return;
  int j = i % (KP / 4);
  int v = i / (KP / 4);
  float4 f = make_float4(0.f, 0.f, 0.f, 0.f);
  if (j < D_IN / 4) f = ((const float4*)(x + (size_t)v * D_IN))[j];
  float dv = dinv[v];
  bf16x4 o;
  o[0] = (bf16)(f.x * dv); o[1] = (bf16)(f.y * dv); o[2] = (bf16)(f.z * dv); o[3] = (bf16)(f.w * dv);
  *(bf16x4*)(Xs + (size_t)v * KP + j * 4) = o;
}

// Wt[n][k] = W[k][n], zero-padded to [KP][KP]
__global__ __launch_bounds__(256) void k_conv_w(const float* __restrict__ W, bf16* __restrict__ Wt,
                                                int Kin, int Nin) {
  int i = blockIdx.x * 256 + threadIdx.x;
  if (i >= KP * KP) return;
  int k = i % KP;
  int n = i / KP;
  float f = (k < Kin && n < Nin) ? W[k * Nin + n] : 0.f;
  Wt[i] = (bf16)f;
}

// ---------------- aggregation (pre-GEMM, bf16): out[v] = dinv[v]*(sum_nbr in[u] + in[v]) ----------------
// R4 form (VGPR 32, occ ~73%): lanes 0..39 own 8 cols; x4 unroll, 2 acc sets.

__global__ __launch_bounds__(256) void k_aggb(const bf16* __restrict__ in, const int* __restrict__ rp,
                                              const int* __restrict__ col, const float* __restrict__ dinv,
                                              bf16* __restrict__ out) {
  int w = threadIdx.x >> 6, l = threadIdx.x & 63;
  int v = blockIdx.x * 4 + w;
  if (v >= N_NODES) return;
  if (l >= 40) return;                         // 40 lanes x 8 cols = 320
  const size_t co = (size_t)8 * l;

  float A0[8], A1[8];
  {                                            // init with self row
    bf16x8 p = *(const bf16x8*)(in + (size_t)v * KP + co);
#pragma unroll
    for (int j = 0; j < 8; ++j) { A0[j] = (float)p[j]; A1[j] = 0.f; }
  }
  int s = rp[v], e = rp[v + 1];
  int i = s;
  for (; i + 4 <= e; i += 4) {
    int u0 = col[i], u1 = col[i + 1], u2 = col[i + 2], u3 = col[i + 3];
    bf16x8 p0 = *(const bf16x8*)(in + (size_t)u0 * KP + co);
    bf16x8 p1 = *(const bf16x8*)(in + (size_t)u1 * KP + co);
    bf16x8 p2 = *(const bf16x8*)(in + (size_t)u2 * KP + co);
    bf16x8 p3 = *(const bf16x8*)(in + (size_t)u3 * KP + co);
#pragma unroll
    for (int j = 0; j < 8; ++j) {
      A0[j] += (float)p0[j] + (float)p2[j];
      A1[j] += (float)p1[j] + (float)p3[j];
    }
  }
  for (; i + 2 <= e; i += 2) {
    int u0 = col[i], u1 = col[i + 1];
    bf16x8 p0 = *(const bf16x8*)(in + (size_t)u0 * KP + co);
    bf16x8 p1 = *(const bf16x8*)(in + (size_t)u1 * KP + co);
#pragma unroll
    for (int j = 0; j < 8; ++j) { A0[j] += (float)p0[j]; A1[j] += (float)p1[j]; }
  }
  if (i < e) {
    int u0 = col[i];
    bf16x8 p0 = *(const bf16x8*)(in + (size_t)u0 * KP + co);
#pragma unroll
    for (int j = 0; j < 8; ++j) A0[j] += (float)p0[j];
  }
  float dv = dinv[v];
  bf16x8 o;
#pragma unroll
  for (int j = 0; j < 8; ++j) o[j] = (bf16)((A0[j] + A1[j]) * dv);
  *(bf16x8*)(out + (size_t)v * KP + co) = o;
}

// ---------------- layer-3 post-GEMM aggregation ----------------
// T3: [NPAD][128] bf16. T3[u] = (H·W3)[u] = dinv[u]*(h2·W3)[u] — already gather-prescaled.
// sArr[v] = sum_d relu(dinv[v]*(sum_nbr T3[u] + T3[v])[d] + b3[d]) * Wm[d]

__global__ __launch_bounds__(256) void k_agg3(const bf16* __restrict__ T3, const int* __restrict__ rp,
                                              const int* __restrict__ col, const float* __restrict__ dinv,
                                              const float* __restrict__ bias, const float* __restrict__ Wm,
                                              float* __restrict__ sArr) {
  const int tid = threadIdx.x;
  const int c = tid & 15;                      // 16B chunk within row
  const int v = blockIdx.x * 16 + (tid >> 4);  // grid is exactly N_NODES/16
  const size_t co = (size_t)8 * c;

  float A0[8], A1[8];
  {                                            // self row
    bf16x8 p = *(const bf16x8*)(T3 + (size_t)v * 128 + co);
#pragma unroll
    for (int j = 0; j < 8; ++j) { A0[j] = (float)p[j]; A1[j] = 0.f; }
  }
  int s = rp[v], e = rp[v + 1];
  int i = s;
  for (; i + 4 <= e; i += 4) {
    int u0 = col[i], u1 = col[i + 1], u2 = col[i + 2], u3 = col[i + 3];
    bf16x8 p0 = *(const bf16x8*)(T3 + (size_t)u0 * 128 + co);
    bf16x8 p1 = *(const bf16x8*)(T3 + (size_t)u1 * 128 + co);
    bf16x8 p2 = *(const bf16x8*)(T3 + (size_t)u2 * 128 + co);
    bf16x8 p3 = *(const bf16x8*)(T3 + (size_t)u3 * 128 + co);
#pragma unroll
    for (int j = 0; j < 8; ++j) {
      A0[j] += (float)p0[j] + (float)p2[j];
      A1[j] += (float)p1[j] + (float)p3[j];
    }
  }
  for (; i + 2 <= e; i += 2) {
    int u0 = col[i], u1 = col[i + 1];
    bf16x8 p0 = *(const bf16x8*)(T3 + (size_t)u0 * 128 + co);
    bf16x8 p1 = *(const bf16x8*)(T3 + (size_t)u1 * 128 + co);
#pragma unroll
    for (int j = 0; j < 8; ++j) { A0[j] += (float)p0[j]; A1[j] += (float)p1[j]; }
  }
  if (i < e) {
    bf16x8 p0 = *(const bf16x8*)(T3 + (size_t)col[i] * 128 + co);
#pragma unroll
    for (int j = 0; j < 8; ++j) A0[j] += (float)p0[j];
  }

  float dv = dinv[v];
  float sv = 0.f;
#pragma unroll
  for (int j = 0; j < 8; ++j) {
    int d = (int)co + j;
    float val = fmaxf((A0[j] + A1[j]) * dv + bias[d], 0.f);
    sv += val * Wm[d];
  }
#pragma unroll
  for (int m = 1; m < 16; m <<= 1) sv += __shfl_xor(sv, m);  // reduce within 16-lane group
  if (c == 0) sArr[v] = sv;
}

// ---------------- GEMM (R7 structure): M-tile 128 x NP, K split 5x64, 8 waves ----------------
// NOTE (R8 journal): BK=32 double-buffered "pipeline" regressed +40us — __syncthreads drains
// vmcnt(0) so the prefetch is serialized anyway; keep the 2-barrier/chunk BK=64 form.
// A: [NPAD][KP] bf16 k-contig. Bt: [KP][KP] bf16 n-major k-contig.
// LDS rows are 128B k-chunks, XOR-swizzled via pre-swizzled GLOBAL source; un-swizzled on ds_read.
// EPI 0: H[row][c] = dinv[row]*relu(acc + bias[c])   (bf16, stride KP)
// EPI 1: T3[row][c] = acc                            (bf16, stride NP; input rows carry dinv)

template <int NP, int WM, int WN, int EPI>
__global__ __launch_bounds__(512, 4) void k_gemm(const bf16* __restrict__ A, const bf16* __restrict__ Bt,
                                                 const float* __restrict__ dinv, const float* __restrict__ bias,
                                                 bf16* __restrict__ H) {
  constexpr int WROWS = MT / WM;
  constexpr int MI    = WROWS / 16;
  constexpr int WCOLS = NP / WN;
  constexpr int NC    = WCOLS / 16;
  constexpr int NB_B  = NP / 64;
  __shared__ __attribute__((aligned(16))) char sA[MT * 128];   // 16 KB
  __shared__ __attribute__((aligned(16))) char sB[NP * 128];   // 40/16 KB

  const int tid = threadIdx.x;
  const int w = tid >> 6, l = tid & 63;
  const int wm = w / WN, wn = w % WN;
  const int m0 = blockIdx.x * MT;

  const int sr  = tid >> 3;                      // staging row 0..63 per 64-row group
  const int ssw = ((tid & 7) << 4) ^ ((sr & 7) << 4);
  const char* Ab = (const char*)A;
  const char* Bb = (const char*)Bt;

  const int la = l & 15, q = l >> 4;
  const int msk = (la & 7) << 4;                 // read-side swizzle

  f32x4 acc[MI][NC] = {};

  for (int kh = 0; kh < 5; ++kh) {
#pragma unroll
    for (int i = 0; i < 2; ++i) {
      const char* src = Ab + (size_t)(m0 + i * 64 + sr) * 640 + kh * 128 + ssw;
      __builtin_amdgcn_global_load_lds(AS1(src), AS3(sA + i * 8192 + w * 1024), 16, 0, 0);
    }
#pragma unroll
    for (int i = 0; i < NB_B; ++i) {
      const char* src = Bb + (size_t)(i * 64 + sr) * 640 + kh * 128 + ssw;
      __builtin_amdgcn_global_load_lds(AS1(src), AS3(sB + i * 8192 + w * 1024), 16, 0, 0);
    }
    __syncthreads();

#pragma unroll
    for (int ks = 0; ks < 2; ++ks) {
      const int cb = (ks * 64 + q * 16) ^ msk;
      bf16x8 af[MI];
#pragma unroll
      for (int mi = 0; mi < MI; ++mi) {
        int r = wm * WROWS + mi * 16 + la;
        af[mi] = *(const bf16x8*)(sA + r * 128 + cb);
      }
#pragma unroll
      for (int nc = 0; nc < NC; ++nc) {
        int rb = wn * WCOLS + nc * 16 + la;
        bf16x8 bfr = *(const bf16x8*)(sB + rb * 128 + cb);
#pragma unroll
        for (int mi = 0; mi < MI; ++mi)
          acc[mi][nc] = __builtin_amdgcn_mfma_f32_16x16x32_bf16(af[mi], bfr, acc[mi][nc], 0, 0, 0);
      }
    }
    __syncthreads();
  }

  // C/D layout: col = lane&15, row = (lane>>4)*4 + reg
  const int rbase = m0 + wm * WROWS + q * 4;
  if (EPI == 0) {
    float bc[NC];
#pragma unroll
    for (int nc = 0; nc < NC; ++nc) {
      int c = wn * WCOLS + nc * 16 + la;
      bc[nc] = (c < D_HID) ? bias[c] : 0.f;      // pad cols: acc=0, bias=0 -> stores 0
    }
#pragma unroll
    for (int mi = 0; mi < MI; ++mi) {
#pragma unroll
      for (int r = 0; r < 4; ++r) {
        int row = rbase + mi * 16 + r;
        if (row < N_NODES) {
          float dv = dinv[row];
#pragma unroll
          for (int nc = 0; nc < NC; ++nc) {
            int c = wn * WCOLS + nc * 16 + la;
            H[(size_t)row * KP + c] = (bf16)(fmaxf(acc[mi][nc][r] + bc[nc], 0.f) * dv);
          }
        }
      }
    }
  } else {
#pragma unroll
    for (int mi = 0; mi < MI; ++mi) {
#pragma unroll
      for (int r = 0; r < 4; ++r) {
        int row = rbase + mi * 16 + r;
        if (row < N_NODES) {
#pragma unroll
          for (int nc = 0; nc < NC; ++nc) {
            int c = wn * WCOLS + nc * 16 + la;
            H[(size_t)row * NP + c] = (bf16)acc[mi][nc][r];   // NO dinv: input rows already scaled
          }
        }
      }
    }
  }
}

// ---------------- pooled reduction ----------------

__global__ __launch_bounds__(256) void k_gsum(const float* __restrict__ sArr, const int* __restrict__ batch,
                                              float* __restrict__ gsum, int* __restrict__ cnt) {
  __shared__ float lsum[N_GRAPHS];
  __shared__ int   lcnt[N_GRAPHS];
  int tid = threadIdx.x;
  lsum[tid] = 0.f; lsum[tid + 256] = 0.f;
  lcnt[tid] = 0;   lcnt[tid + 256] = 0;
  __syncthreads();
  int v = blockIdx.x * 256 + tid;
  if (v < N_NODES) {
    int b = batch[v];
    atomicAdd(&lsum[b], sArr[v]);
    atomicAdd(&lcnt[b], 1);
  }
  __syncthreads();
  // sorted batch -> nonzero slots confined to [g0, g1]
  int v0 = blockIdx.x * 256;
  int v1 = min(v0 + 255, N_NODES - 1);
  int g0 = batch[v0], g1 = batch[v1];
  for (int g = g0 + tid; g <= g1; g += 256) {
    int c = lcnt[g];
    if (c) { atomicAdd(&gsum[g], lsum[g]); atomicAdd(&cnt[g], c); }
  }
}

__global__ __launch_bounds__(512) void k_final(const float* __restrict__ gsum, const int* __restrict__ cnt,
                                               const float* __restrict__ bm, float* __restrict__ out) {
  int g = blockIdx.x * 512 + threadIdx.x;
  if (g < N_GRAPHS) out[g] = gsum[g] / fmaxf((float)cnt[g], 1.f) + bm[0];
}

// ---------------- launch ----------------

extern "C" void kernel_launch(void* const* d_in, const int* in_sizes, int n_in,
                              void* d_out, int out_size, void* d_ws, size_t ws_size,
                              hipStream_t stream) {
  const float* x    = (const float*)d_in[0];
  const int*   ei   = (const int*)d_in[1];
  const int*   batch= (const int*)d_in[2];
  const float* W1   = (const float*)d_in[3];
  const float* b1   = (const float*)d_in[4];
  const float* W2   = (const float*)d_in[5];
  const float* b2   = (const float*)d_in[6];
  const float* W3   = (const float*)d_in[7];
  const float* b3   = (const float*)d_in[8];
  const float* Wm   = (const float*)d_in[9];
  const float* bm   = (const float*)d_in[10];
  float* out = (float*)d_out;

  char* ws = (char*)d_ws;
  size_t off = 0;
  auto alloc = [&](size_t bytes) {
    void* p = ws + off;
    off = (off + bytes + 255) & ~(size_t)255;
    return p;
  };
  bf16*  Xs   = (bf16*)alloc((size_t)NPAD * KP * sizeof(bf16));    // 64 MB; reused as H
  bf16*  Ab   = (bf16*)alloc((size_t)NPAD * KP * sizeof(bf16));    // 64 MB
  bf16*  T3   = (bf16*)alloc((size_t)NPAD * 128 * sizeof(bf16));   // 25.6 MB
  bf16*  Wt   = (bf16*)alloc((size_t)KP * KP * sizeof(bf16));
  int*   deg  = (int*)alloc((size_t)N_NODES * 4);
  float* dinv = (float*)alloc((size_t)N_NODES * 4);
  int*   rp   = (int*)alloc((size_t)(N_NODES + 1) * 4);
  int*   cur  = (int*)alloc((size_t)N_NODES * 4);
  int*   col  = (int*)alloc((size_t)N_EDGES * 4);
  int*   part = (int*)alloc(1024 * 4);
  float* sArr = (float*)alloc((size_t)N_NODES * 4);
  float* gsum = (float*)alloc((size_t)N_GRAPHS * 4);
  int*   cnt  = (int*)alloc((size_t)N_GRAPHS * 4);
  bf16*  H    = Xs;   // Xs dead after layer-1 agg

  int nbN = (N_NODES + 255) / 256;       // 391
  int nbE4 = (N_EDGES / 4 + 255) / 256;  // 782
  int nbA = (N_NODES + 3) / 4;           // 25000
  int nbW = (KP * KP + 255) / 256;

  k_init<<<nbN, 256, 0, stream>>>(deg, gsum, cnt);
  k_deg<<<nbE4, 256, 0, stream>>>(ei, deg);
  k_scan1<<<nbN, 256, 0, stream>>>(deg, rp, part);
  k_scan2<<<1, 512, 0, stream>>>(part, nbN);
  k_scan3<<<nbN, 256, 0, stream>>>(rp, part, cur, deg, dinv);
  k_fill<<<nbE4, 256, 0, stream>>>(ei, cur, col);
  k_conv_x<<<(N_NODES * (KP / 4) + 255) / 256, 256, 0, stream>>>(x, dinv, Xs);

  // layer 1: aggregate (bf16) -> GEMM (bias+relu+dinv)
  k_conv_w<<<nbW, 256, 0, stream>>>(W1, Wt, 300, 300);
  k_aggb<<<nbA, 256, 0, stream>>>(Xs, rp, col, dinv, Ab);
  k_gemm<KP, 2, 4, 0><<<NTILE, 512, 0, stream>>>(Ab, Wt, dinv, b1, H);
  // layer 2
  k_conv_w<<<nbW, 256, 0, stream>>>(W2, Wt, 300, 300);
  k_aggb<<<nbA, 256, 0, stream>>>(H, rp, col, dinv, Ab);
  k_gemm<KP, 2, 4, 0><<<NTILE, 512, 0, stream>>>(Ab, Wt, dinv, b2, H);
  // layer 3: GEMM first (128-wide; H rows already dinv-scaled), then aggregate + bias + relu + Wm-dot
  k_conv_w<<<nbW, 256, 0, stream>>>(W3, Wt, 300, 128);
  k_gemm<128, 8, 1, 1><<<NTILE, 512, 0, stream>>>(H, Wt, dinv, nullptr, T3);
  k_agg3<<<N_NODES / 16, 256, 0, stream>>>(T3, rp, col, dinv, b3, Wm, sArr);

  k_gsum<<<nbN, 256, 0, stream>>>(sArr, batch, gsum, cnt);
  k_final<<<1, 512, 0, stream>>>(gsum, cnt, bm, out);
}